// Round 1
// 342.951 us; speedup vs baseline: 1.0274x; 1.0274x over previous
//
#include <hip/hip_runtime.h>
#include <hip/hip_bf16.h>

// SplitMLP: B=128, C=16, V=32, H=64, O=4, G=10000
// Block = 256 thr / 4 waves, GPB=4 consecutive groups (grid 2500).
// v2: latency-bound fix. All per-group globals are software-pipelined one group
// ahead (W1, b1, items) or issued at iteration top (W2); day hoisted pre-loop.
// __syncthreads() replaced with raw s_barrier + lgkmcnt(0)-only waits so the
// in-flight prefetch loads are NOT drained at barriers (hipcc's __syncthreads
// emits s_waitcnt vmcnt(0) which killed the previous pipeline).
// fc1 flipped: h^T = W1 @ A^T (M=64 hidden, N=batch, K=48->64 zero-padded).
// fc2: y^T = W2 @ h^T; h^T round-trips wave-private LDS. b1 added in f32 via
// LDS broadcast (exact numerics); b2 added in f32 at the final 64B-line store.

typedef __bf16 v8bf __attribute__((ext_vector_type(8)));
typedef __bf16 v4bf __attribute__((ext_vector_type(4)));
typedef float  v4f  __attribute__((ext_vector_type(4)));

#define B_   128
#define C_   16
#define V_   32
#define H_   64
#define O_   4
#define G_   10000
#define GPB  4
#define WS_  56   // W1s stride (elems): 112B = 16B-aligned rows, 2-way banks (free)
#define HS_  72   // Hb stride: 144B = 16B-aligned, 2-way banks
#define YS_  20   // Ybuf stride (f32): 80B, float4-aligned

__device__ __forceinline__ v4bf cvt4(float4 f) {
  v4bf r;
  r[0] = (__bf16)f.x; r[1] = (__bf16)f.y; r[2] = (__bf16)f.z; r[3] = (__bf16)f.w;
  return r;
}
__device__ __forceinline__ v8bf cvt8(float4 lo, float4 hi) {
  v8bf r;
  r[0] = (__bf16)lo.x; r[1] = (__bf16)lo.y; r[2] = (__bf16)lo.z; r[3] = (__bf16)lo.w;
  r[4] = (__bf16)hi.x; r[5] = (__bf16)hi.y; r[6] = (__bf16)hi.z; r[7] = (__bf16)hi.w;
  return r;
}
__device__ __forceinline__ v8bf gload8(const float* __restrict__ p) {
  const float4* p4 = reinterpret_cast<const float4*>(p);
  return cvt8(p4[0], p4[1]);
}

__global__ __launch_bounds__(256, 4)
void splitmlp_kernel(const float* __restrict__ day,
                     const float* __restrict__ items,
                     const float* __restrict__ W1d,
                     const float* __restrict__ W1v,
                     const float* __restrict__ b1,
                     const float* __restrict__ W2,
                     const float* __restrict__ b2,
                     float* __restrict__ out) {
  __shared__ __bf16 W1s[H_ * WS_];        //  7,168 B  [h][k 0..48)
  __shared__ float  B1s[H_];              //    256 B  f32 bias broadcast
  __shared__ __bf16 Hb[4][32 * HS_];      // 18,432 B  per-wave [batch32][hidden64]
  __shared__ float  Yb[B_ * YS_];         // 10,240 B  [b][16 used]

  const int t    = threadIdx.x;
  const int g0   = blockIdx.x * GPB;
  const int w    = t >> 6;
  const int lane = t & 63;
  const int c    = lane & 15;
  const int q    = lane >> 4;
  const int wbase = w * 32;

  v8bf zf;
#pragma unroll
  for (int i = 0; i < 8; ++i) zf[i] = (__bf16)0.0f;
  const v4f zero = {0.f, 0.f, 0.f, 0.f};

  // ---- day frags: group-invariant — load + convert ONCE ----
  v8bf dayf[2];
#pragma unroll
  for (int nb = 0; nb < 2; ++nb) {
    const int b = wbase + nb * 16 + c;
    dayf[nb] = (q < 2) ? gload8(day + b * C_ + q * 8) : zf;
  }

  // ---- cross-group register prefetch for group g0: W1, b1, items ----
  float4 pd, pv0, pv1;
  float  pb1;
  {
    const float* W1dg = W1d + (size_t)g0 * (H_ * C_);
    const float* W1vg = W1v + (size_t)g0 * (H_ * V_);
    pd  = reinterpret_cast<const float4*>(W1dg)[t];
    pv0 = reinterpret_cast<const float4*>(W1vg)[t];
    pv1 = reinterpret_cast<const float4*>(W1vg)[t + 256];
    pb1 = b1[(size_t)g0 * H_ + (t & 63)];
  }
  // items: each lane owns exactly 8 floats per batch-half.
  // frag0 k=q*8 (q>=2 -> items[0..15]); frag1 k=32+q*8 (q<2 -> items[16..31]).
  const int ioff = ((q + 2) & 3) * 8;   // q:0,1,2,3 -> 16,24,0,8
  const float* pit0 = items + (size_t)(wbase + c) * (G_ * V_) + (size_t)g0 * V_ + ioff;
  const float* pit1 = pit0 + (size_t)16 * (G_ * V_);
  float4 it[2][2];
  it[0][0] = reinterpret_cast<const float4*>(pit0)[0];
  it[0][1] = reinterpret_cast<const float4*>(pit0)[1];
  it[1][0] = reinterpret_cast<const float4*>(pit1)[0];
  it[1][1] = reinterpret_cast<const float4*>(pit1)[1];

#pragma unroll 1
  for (int gi = 0; gi < GPB; ++gi) {
    const int g = g0 + gi;

    // barrier A (raw): all waves done READING W1s/B1s of previous group.
    // lgkmcnt(0) only — in-flight global prefetch loads stay outstanding.
    asm volatile("s_waitcnt lgkmcnt(0)" ::: "memory");
    __builtin_amdgcn_s_barrier();
    asm volatile("" ::: "memory");

    // ---- stage W1(g)+b1(g) from prefetch regs (compiler emits use-site vmcnt) ----
    {
      const int hd = t >> 2, kd = (t & 3) << 2;
      *reinterpret_cast<v4bf*>(&W1s[hd * WS_ + kd]) = cvt4(pd);
      const int hv0 = t >> 3, kv0 = C_ + ((t & 7) << 2);
      *reinterpret_cast<v4bf*>(&W1s[hv0 * WS_ + kv0]) = cvt4(pv0);
      const int i2 = t + 256;
      const int hv1 = i2 >> 3, kv1 = C_ + ((i2 & 7) << 2);
      *reinterpret_cast<v4bf*>(&W1s[hv1 * WS_ + kv1]) = cvt4(pv1);
      if (t < H_) B1s[t] = pb1;
    }

    // issue W2(g) now — consumed at fc2, so fc1 covers its latency.
    // address clamped with c&3 so the load is unconditional and in-bounds.
    float4 w2r[2][2];
    {
      const float* pw2 = W2 + (size_t)g * (O_ * H_) + (c & 3) * H_ + q * 8;
      w2r[0][0] = reinterpret_cast<const float4*>(pw2)[0];
      w2r[0][1] = reinterpret_cast<const float4*>(pw2)[1];
      w2r[1][0] = reinterpret_cast<const float4*>(pw2 + 32)[0];
      w2r[1][1] = reinterpret_cast<const float4*>(pw2 + 32)[1];
    }
    // issue next group's W1/b1 prefetch (lands during this group's compute).
    if (gi < GPB - 1) {
      const float* W1dn = W1d + (size_t)(g + 1) * (H_ * C_);
      const float* W1vn = W1v + (size_t)(g + 1) * (H_ * V_);
      pd  = reinterpret_cast<const float4*>(W1dn)[t];
      pv0 = reinterpret_cast<const float4*>(W1vn)[t];
      pv1 = reinterpret_cast<const float4*>(W1vn)[t + 256];
      pb1 = b1[(size_t)(g + 1) * H_ + (t & 63)];
    }

    // barrier B (raw): W1s/B1s(g) visible to all waves; NO vmcnt drain.
    asm volatile("s_waitcnt lgkmcnt(0)" ::: "memory");
    __builtin_amdgcn_s_barrier();
    asm volatile("" ::: "memory");

    // ---- bfrags from prefetched items (issued one group ago) + day regs ----
    v8bf bl[2], bh[2];
#pragma unroll
    for (int nb = 0; nb < 2; ++nb) {
      const v8bf ic = cvt8(it[nb][0], it[nb][1]);
      bl[nb] = (q < 2) ? dayf[nb] : ic;
      bh[nb] = (q < 2) ? ic : zf;
    }

    // ---- fc1 MFMA: D[hidden][batch], W1 frags streamed from LDS per m ----
    v4f acc[4][2];
#pragma unroll
    for (int m = 0; m < 4; ++m)
#pragma unroll
      for (int nb = 0; nb < 2; ++nb) acc[m][nb] = zero;
#pragma unroll
    for (int m = 0; m < 4; ++m) {
      const int row = (m * 16 + c) * WS_;
      const v8bf w0 = *reinterpret_cast<const v8bf*>(&W1s[row + q * 8]);
      const v8bf w1 = (q < 2) ? *reinterpret_cast<const v8bf*>(&W1s[row + 32 + q * 8]) : zf;
#pragma unroll
      for (int nb = 0; nb < 2; ++nb) {
        acc[m][nb] = __builtin_amdgcn_mfma_f32_16x16x32_bf16(w0, bl[nb], acc[m][nb], 0, 0, 0);
        acc[m][nb] = __builtin_amdgcn_mfma_f32_16x16x32_bf16(w1, bh[nb], acc[m][nb], 0, 0, 0);
      }
    }

    // issue next group's items loads — consumed NEXT iteration, so the
    // epilogue+fc2+stage phases (and barrier crossing) cover their latency.
    if (gi < GPB - 1) {
      pit0 += V_;
      pit1 += V_;
      it[0][0] = reinterpret_cast<const float4*>(pit0)[0];
      it[0][1] = reinterpret_cast<const float4*>(pit0)[1];
      it[1][0] = reinterpret_cast<const float4*>(pit1)[0];
      it[1][1] = reinterpret_cast<const float4*>(pit1)[1];
    }

    // ---- epilogue: +b1 (f32 via B1s broadcast), ReLU, packed b64 -> Hb ----
#pragma unroll
    for (int m = 0; m < 4; ++m) {
      const float4 bb = *reinterpret_cast<const float4*>(&B1s[m * 16 + q * 4]);
#pragma unroll
      for (int nb = 0; nb < 2; ++nb) {
        v4bf hv;
        hv[0] = (__bf16)fmaxf(acc[m][nb][0] + bb.x, 0.f);
        hv[1] = (__bf16)fmaxf(acc[m][nb][1] + bb.y, 0.f);
        hv[2] = (__bf16)fmaxf(acc[m][nb][2] + bb.z, 0.f);
        hv[3] = (__bf16)fmaxf(acc[m][nb][3] + bb.w, 0.f);
        *reinterpret_cast<v4bf*>(&Hb[w][(nb * 16 + c) * HS_ + m * 16 + q * 4]) = hv;
      }
    }

    // ---- fc2: y^T = W2(pad16) @ h^T (W2 regs were issued at iteration top) ----
    v4f y[2] = {zero, zero};
#pragma unroll
    for (int kt = 0; kt < 2; ++kt) {
      const v8bf w2f = (c < O_) ? cvt8(w2r[kt][0], w2r[kt][1]) : zf;
#pragma unroll
      for (int nb = 0; nb < 2; ++nb) {
        const v8bf hf = *reinterpret_cast<const v8bf*>(&Hb[w][(nb * 16 + c) * HS_ + kt * 32 + q * 8]);
        y[nb] = __builtin_amdgcn_mfma_f32_16x16x32_bf16(w2f, hf, y[nb], 0, 0, 0);
      }
    }

    // ---- y -> Ybuf (q==0 lanes hold o=0..3 as regs r); b2 added at final store ----
    if (q == 0) {
#pragma unroll
      for (int nb = 0; nb < 2; ++nb) {
        const int b = wbase + nb * 16 + c;
        float4 o;
        o.x = y[nb][0]; o.y = y[nb][1]; o.z = y[nb][2]; o.w = y[nb][3];
        *reinterpret_cast<float4*>(&Yb[b * YS_ + gi * 4]) = o;
      }
    }
  }

  __syncthreads();
  // cooperative output store: full 64B line per 4-lane cluster, +b2 in f32
#pragma unroll
  for (int i = t; i < 512; i += 256) {
    const int b = i >> 2, c4 = i & 3;
    const float4 bv = *reinterpret_cast<const float4*>(b2 + (size_t)(g0 + c4) * O_);
    float4 v = *reinterpret_cast<const float4*>(&Yb[b * YS_ + c4 * 4]);
    v.x += bv.x; v.y += bv.y; v.z += bv.z; v.w += bv.w;
    *reinterpret_cast<float4*>(out + (size_t)b * (G_ * O_) + (size_t)g0 * O_ + c4 * 4) = v;
  }
}

extern "C" void kernel_launch(void* const* d_in, const int* in_sizes, int n_in,
                              void* d_out, int out_size, void* d_ws, size_t ws_size,
                              hipStream_t stream) {
  const float* day   = (const float*)d_in[0];
  const float* items = (const float*)d_in[1];
  const float* W1d   = (const float*)d_in[2];
  const float* W1v   = (const float*)d_in[3];
  const float* b1    = (const float*)d_in[4];
  const float* W2    = (const float*)d_in[5];
  const float* b2    = (const float*)d_in[6];
  float* out = (float*)d_out;
  splitmlp_kernel<<<G_ / GPB, 256, 0, stream>>>(day, items, W1d, W1v, b1, W2, b2, out);
}

// Round 2
// 338.866 us; speedup vs baseline: 1.0398x; 1.0121x over previous
//
#include <hip/hip_runtime.h>
#include <hip/hip_bf16.h>

// SplitMLP: B=128, C=16, V=32, H=64, O=4, G=10000
// v3: BARRIER-FREE waves. Theory: v1/v2 were stalled by 2 block-wide barriers
// per group-iteration (W1-in-LDS sharing forced lockstep; ~zero loads in flight
// during barrier convergence -> all pipes <11% busy at 17% HBM).
// New structure: one wave = one whole group (4 waves/block = GPB=4 groups),
// batch dim processed as 8 N-tiles of 16. W1 loaded per-wave direct from global
// into MFMA A-frags (same total traffic, fully coalesced). day staged to LDS
// once per block (single startup barrier, lgkm-only). Hb transpose buffer is
// wave-private (no barriers). Output stored direct to global (16B/lane, the 4
// waves of a block dirty the 4 quarters of each 64B line within the block's
// lifetime -> L2 merges). In-loop barriers: ZERO.

typedef __bf16 v8bf __attribute__((ext_vector_type(8)));
typedef __bf16 v4bf __attribute__((ext_vector_type(4)));
typedef float  v4f  __attribute__((ext_vector_type(4)));

#define B_   128
#define C_   16
#define V_   32
#define H_   64
#define O_   4
#define G_   10000
#define GPB  4
#define DS_  24   // Dl stride (elems): 48B rows -> 16B-aligned, ~2-way banks (free)
#define HS_  72   // Hb stride (elems): 144B -> 16B-aligned, 2-way banks (free)

__device__ __forceinline__ v4bf cvt4(float4 f) {
  v4bf r;
  r[0] = (__bf16)f.x; r[1] = (__bf16)f.y; r[2] = (__bf16)f.z; r[3] = (__bf16)f.w;
  return r;
}
__device__ __forceinline__ v8bf cvt8(float4 lo, float4 hi) {
  v8bf r;
  r[0] = (__bf16)lo.x; r[1] = (__bf16)lo.y; r[2] = (__bf16)lo.z; r[3] = (__bf16)lo.w;
  r[4] = (__bf16)hi.x; r[5] = (__bf16)hi.y; r[6] = (__bf16)hi.z; r[7] = (__bf16)hi.w;
  return r;
}

__global__ __launch_bounds__(256, 4)
void splitmlp_kernel(const float* __restrict__ day,
                     const float* __restrict__ items,
                     const float* __restrict__ W1d,
                     const float* __restrict__ W1v,
                     const float* __restrict__ b1,
                     const float* __restrict__ W2,
                     const float* __restrict__ b2,
                     float* __restrict__ out) {
  __shared__ __bf16 Dl[B_ * DS_];       //  6,144 B  day bf16 [b][16 used]
  __shared__ __bf16 Hb[4][16 * HS_];    //  9,216 B  per-wave h [batch16][hidden64]

  const int t    = threadIdx.x;
  const int w    = t >> 6;
  const int lane = t & 63;
  const int c    = lane & 15;
  const int q    = lane >> 4;
  const int g    = blockIdx.x * GPB + w;   // this wave's group

  v8bf zf;
#pragma unroll
  for (int i = 0; i < 8; ++i) zf[i] = (__bf16)0.0f;
  const v4f zero = {0.f, 0.f, 0.f, 0.f};

  // ---- day global loads first (feed the one-time LDS stage) ----
  float4 dd[2];
  {
    const float4* d4 = reinterpret_cast<const float4*>(day);
    dd[0] = d4[t];
    dd[1] = d4[t + 256];
  }

  // ---- task-start load burst: W1, W2, b1, b2, items tile-0 (all in flight) ----
  const float* W1dg = W1d + (size_t)g * (H_ * C_);
  const float* W1vg = W1v + (size_t)g * (H_ * V_);
  float4 s0[4][2], s1[4][2];
#pragma unroll
  for (int m = 0; m < 4; ++m) {
    const int h = m * 16 + c;
    // frag0 k=q*8: q<2 -> W1d[h][q*8..+8); q>=2 -> W1v[h][(q-2)*8..+8)
    const float* p0 = (q < 2) ? (W1dg + h * C_ + q * 8) : (W1vg + h * V_ + (q - 2) * 8);
    s0[m][0] = reinterpret_cast<const float4*>(p0)[0];
    s0[m][1] = reinterpret_cast<const float4*>(p0)[1];
  }
#pragma unroll
  for (int m = 0; m < 4; ++m) {
    // frag1 k=32+q*8: q<2 -> W1v[h][16+q*8..+8); q>=2 lanes contribute zero
    if (q < 2) {
      const float* p1 = W1vg + (m * 16 + c) * V_ + 16 + q * 8;
      s1[m][0] = reinterpret_cast<const float4*>(p1)[0];
      s1[m][1] = reinterpret_cast<const float4*>(p1)[1];
    }
  }
  float4 w2s[2][2];
  {
    const float* pw2 = W2 + (size_t)g * (O_ * H_) + (c & 3) * H_ + q * 8;
    w2s[0][0] = reinterpret_cast<const float4*>(pw2)[0];
    w2s[0][1] = reinterpret_cast<const float4*>(pw2)[1];
    w2s[1][0] = reinterpret_cast<const float4*>(pw2 + 32)[0];
    w2s[1][1] = reinterpret_cast<const float4*>(pw2 + 32)[1];
  }
  float4 bb[4];
#pragma unroll
  for (int m = 0; m < 4; ++m)
    bb[m] = *reinterpret_cast<const float4*>(b1 + (size_t)g * H_ + m * 16 + q * 4);
  const float4 b2v = *reinterpret_cast<const float4*>(b2 + (size_t)g * O_);

  // items: lane(c,q) owns 8 consecutive floats of batch-row (tile*16+c), group g.
  // frag0 q>=2 -> items[(q-2)*8]; frag1 q<2 -> items[16+q*8]  => ioff=((q+2)&3)*8
  const int ioff = ((q + 2) & 3) * 8;
  const float* itbase = items + (size_t)c * (G_ * V_) + (size_t)g * V_ + ioff;
  float4 itA[2], itB[2];
  itA[0] = reinterpret_cast<const float4*>(itbase)[0];
  itA[1] = reinterpret_cast<const float4*>(itbase)[1];

  // ---- stage day -> Dl (one-time), lgkm-only barrier ----
  {
#pragma unroll
    for (int i = 0; i < 2; ++i) {
      const int idx = t + i * 256;
      const int b = idx >> 2, col = (idx & 3) << 2;
      *reinterpret_cast<v4bf*>(&Dl[b * DS_ + col]) = cvt4(dd[i]);
    }
  }
  asm volatile("s_waitcnt lgkmcnt(0)" ::: "memory");
  __builtin_amdgcn_s_barrier();
  asm volatile("" ::: "memory");

  // ---- convert burst -> bf16 fragments (frees f32 staging regs) ----
  v8bf wf0[4], wf1[4], w2f[2];
#pragma unroll
  for (int m = 0; m < 4; ++m) wf0[m] = cvt8(s0[m][0], s0[m][1]);
#pragma unroll
  for (int m = 0; m < 4; ++m) wf1[m] = (q < 2) ? cvt8(s1[m][0], s1[m][1]) : zf;
  w2f[0] = (c < O_) ? cvt8(w2s[0][0], w2s[0][1]) : zf;
  w2f[1] = (c < O_) ? cvt8(w2s[1][0], w2s[1][1]) : zf;

  // ---- 8 N-tiles of 16 batches; rolling items prefetch; ZERO barriers ----
#define CHUNK(CH, CUR, NXT, PREF)                                              \
  {                                                                            \
    if (PREF) {                                                                \
      const float* p = itbase + (size_t)(((CH) + 1) * 16) * (G_ * V_);         \
      NXT[0] = reinterpret_cast<const float4*>(p)[0];                          \
      NXT[1] = reinterpret_cast<const float4*>(p)[1];                          \
    }                                                                          \
    const v8bf dayv =                                                          \
        *reinterpret_cast<const v8bf*>(&Dl[((CH) * 16 + c) * DS_ + (q & 1) * 8]); \
    const v8bf ic  = cvt8(CUR[0], CUR[1]);                                     \
    const v8bf blv = (q < 2) ? dayv : ic;                                      \
    const v8bf bhv = (q < 2) ? ic : zf;                                        \
    v4f acc[4];                                                                \
    _Pragma("unroll")                                                          \
    for (int m = 0; m < 4; ++m) acc[m] = zero;                                 \
    _Pragma("unroll")                                                          \
    for (int m = 0; m < 4; ++m) {                                              \
      acc[m] = __builtin_amdgcn_mfma_f32_16x16x32_bf16(wf0[m], blv, acc[m], 0, 0, 0); \
      acc[m] = __builtin_amdgcn_mfma_f32_16x16x32_bf16(wf1[m], bhv, acc[m], 0, 0, 0); \
    }                                                                          \
    _Pragma("unroll")                                                          \
    for (int m = 0; m < 4; ++m) {                                              \
      v4bf hv;                                                                 \
      hv[0] = (__bf16)fmaxf(acc[m][0] + bb[m].x, 0.f);                         \
      hv[1] = (__bf16)fmaxf(acc[m][1] + bb[m].y, 0.f);                         \
      hv[2] = (__bf16)fmaxf(acc[m][2] + bb[m].z, 0.f);                         \
      hv[3] = (__bf16)fmaxf(acc[m][3] + bb[m].w, 0.f);                         \
      *reinterpret_cast<v4bf*>(&Hb[w][c * HS_ + m * 16 + q * 4]) = hv;         \
    }                                                                          \
    v4f y = zero;                                                              \
    _Pragma("unroll")                                                          \
    for (int kt = 0; kt < 2; ++kt) {                                           \
      const v8bf hf =                                                          \
          *reinterpret_cast<const v8bf*>(&Hb[w][c * HS_ + kt * 32 + q * 8]);   \
      y = __builtin_amdgcn_mfma_f32_16x16x32_bf16(w2f[kt], hf, y, 0, 0, 0);    \
    }                                                                          \
    if (q == 0) {                                                              \
      float4 o;                                                                \
      o.x = y[0] + b2v.x; o.y = y[1] + b2v.y;                                  \
      o.z = y[2] + b2v.z; o.w = y[3] + b2v.w;                                  \
      *reinterpret_cast<float4*>(out + (size_t)((CH) * 16 + c) * (G_ * O_) +   \
                                 (size_t)g * O_) = o;                          \
    }                                                                          \
  }

  CHUNK(0, itA, itB, 1)
  CHUNK(1, itB, itA, 1)
  CHUNK(2, itA, itB, 1)
  CHUNK(3, itB, itA, 1)
  CHUNK(4, itA, itB, 1)
  CHUNK(5, itB, itA, 1)
  CHUNK(6, itA, itB, 1)
  CHUNK(7, itB, itA, 0)
#undef CHUNK
}

extern "C" void kernel_launch(void* const* d_in, const int* in_sizes, int n_in,
                              void* d_out, int out_size, void* d_ws, size_t ws_size,
                              hipStream_t stream) {
  const float* day   = (const float*)d_in[0];
  const float* items = (const float*)d_in[1];
  const float* W1d   = (const float*)d_in[2];
  const float* W1v   = (const float*)d_in[3];
  const float* b1    = (const float*)d_in[4];
  const float* W2    = (const float*)d_in[5];
  const float* b2    = (const float*)d_in[6];
  float* out = (float*)d_out;
  splitmlp_kernel<<<G_ / GPB, 256, 0, stream>>>(day, items, W1d, W1v, b1, W2, b2, out);
}